// Round 17
// baseline (188.359 us; speedup 1.0000x reference)
//
#include <hip/hip_runtime.h>
#include <cstdint>
#include <cstddef>

typedef unsigned short u16;
typedef unsigned int u32;
typedef __attribute__((ext_vector_type(8))) short short8;
typedef __attribute__((ext_vector_type(4))) float f32x4;
typedef __attribute__((ext_vector_type(16))) float f32x16;
typedef __attribute__((ext_vector_type(2))) unsigned int u32x2;

#define CD 256
#define HWD 4096
#define NHD 4
#define HDD 64
#define NSPLIT 4

static __device__ __forceinline__ u16 f2b(float f) {
    u32 u = __builtin_bit_cast(u32, f);
    return (u16)((u + 0x7fffu + ((u >> 16) & 1u)) >> 16);
}
static __device__ __forceinline__ float b2f(u16 h) {
    return __builtin_bit_cast(float, (u32)h << 16);
}
static __device__ __forceinline__ u32 pk2(float a, float b) {
    return (u32)f2b(a) | ((u32)f2b(b) << 16);
}
static __device__ __forceinline__ float fexp2(float x) {
#if __has_builtin(__builtin_amdgcn_exp2f)
    return __builtin_amdgcn_exp2f(x);
#else
    return __expf(x * 0.69314718056f);
#endif
}
// v_cvt_pk_bf16_f32: pack two f32 -> one u32 of 2 bf16 (no builtin on gfx950)
static __device__ __forceinline__ u32 cvtpk(float lo, float hi) {
    u32 r;
    asm("v_cvt_pk_bf16_f32 %0, %1, %2" : "=v"(r) : "v"(lo), "v"(hi));
    return r;
}
// lanes: (a',b') = ([a.lo|b.lo], [a.hi|b.hi])
static __device__ __forceinline__ u32x2 plswap(u32 a, u32 b) {
    return __builtin_amdgcn_permlane32_swap(a, b, false, false);
}
// async global->LDS DMA, 16 B per lane; LDS dest = wave-uniform base + lane*16
static __device__ __forceinline__ void async16(const void* g, void* l) {
    __builtin_amdgcn_global_load_lds(
        (const __attribute__((address_space(1))) unsigned int*)g,
        (__attribute__((address_space(3))) unsigned int*)l,
        16, 0, 0);
}

// ---------------------------------------------------------------------------
// FUSED LayerNorm + conv1x1 GEMM (removes ln_transpose launch + xT/gT
// roundtrip). Block = (ctile, ptile, mm*2+b); the LN of its 32 positions is
// computed in-kernel into a K-resident LDS A tile [32 pos][256 ch]
// (chunk-swizzled), so the K-loop stages only W (fp32 read, L2-hot, pk2
// pack -- the r0-r3-proven path). guide-LN recomputed by k and v blocks
// (identical math -> identical bf16). BK=64, 2 barriers/kt.
// grid (2, 128, 6), block 256. LDS ~36.6 KB -> 4 blocks/CU.
// ---------------------------------------------------------------------------
__global__ __launch_bounds__(256) void ln_qkv_gemm(
    const float* __restrict__ x0, const float* __restrict__ x1,
    const float* __restrict__ g0, const float* __restrict__ b0,
    const float* __restrict__ g1, const float* __restrict__ b1,
    const float* __restrict__ qw1, const float* __restrict__ kw1,
    const float* __restrict__ vw1,
    const float* __restrict__ qb1, const float* __restrict__ kb1,
    const float* __restrict__ vb1,
    u16* __restrict__ q1, u16* __restrict__ k1, u16* __restrict__ v1)
{
    int z = blockIdx.z;
    int mm = z >> 1, b = z & 1;
    const float* x  = (mm == 0) ? x0 : x1;
    const float* g  = (mm == 0) ? g0 : g1;
    const float* bb = (mm == 0) ? b0 : b1;
    const float* W  = (mm == 0) ? qw1 : (mm == 1) ? kw1 : vw1;
    const float* Bi = (mm == 0) ? qb1 : (mm == 1) ? kb1 : vb1;
    u16* Y          = (mm == 0) ? q1 : (mm == 1) ? k1 : v1;

    int n0 = blockIdx.x * 128;   // output-channel tile
    int p0 = blockIdx.y * 32;    // position tile

    __shared__ u16 As[32 * 256];   // [pos][k] chunk-swizzled, 16 KB
    __shared__ u16 Bs[128][72];    // W bf16 staging, 18.4 KB
    __shared__ float red[2][8][32];

    int tid = threadIdx.x;
    int lane = tid & 63, w = tid >> 6;
    int l15 = lane & 15, quad = lane >> 4;
    int sw = l15 & 7;

    // ---- LN phase: position p0+tx, channel slice ty ----
    int tx = tid & 31, ty = tid >> 5;
    const float* xb = x + (size_t)b * CD * HWD + p0 + tx;
    float xv[32];
    float s = 0.f, sq = 0.f;
    #pragma unroll
    for (int i = 0; i < 32; ++i) {
        float v = xb[(size_t)(ty * 32 + i) * HWD];
        xv[i] = v; s += v; sq += v * v;
    }
    red[0][ty][tx] = s; red[1][ty][tx] = sq;
    __syncthreads();
    float st = 0.f, sqt = 0.f;
    #pragma unroll
    for (int j = 0; j < 8; ++j) { st += red[0][j][tx]; sqt += red[1][j][tx]; }
    float mean = st * (1.f / 256.f);
    float var = sqt * (1.f / 256.f) - mean * mean;
    float rstd = rsqrtf(var + 1e-5f);

    // normalize + pack 8 ch at a time into swizzled As (uint4 stores)
    #pragma unroll
    for (int j = 0; j < 4; ++j) {
        float v[8];
        #pragma unroll
        for (int e = 0; e < 8; ++e) {
            int c = ty * 32 + j * 8 + e;
            v[e] = (xv[j * 8 + e] - mean) * rstd * g[c] + bb[c];
        }
        uint4 o;
        o.x = pk2(v[0], v[1]); o.y = pk2(v[2], v[3]);
        o.z = pk2(v[4], v[5]); o.w = pk2(v[6], v[7]);
        int chunk = (ty * 4 + j) ^ (tx & 7);
        *(uint4*)&As[tx * 256 + chunk * 8] = o;
    }

    // ---- W staging regs (fp32, L2-hot): 32 K-ch per thread per kt ----
    int brow = tid >> 1, bkh = (tid & 1) * 32;
    const float* wgp = W + (size_t)(n0 + brow) * CD + bkh;
    float4 rw[8];
    #pragma unroll
    for (int j = 0; j < 8; ++j) rw[j] = ((const float4*)wgp)[j];

    f32x4 acc[2][2];
    #pragma unroll
    for (int mi = 0; mi < 2; ++mi)
        #pragma unroll
        for (int nj = 0; nj < 2; ++nj)
            acc[mi][nj] = (f32x4){0.f, 0.f, 0.f, 0.f};

    for (int kt = 0; kt < 4; ++kt) {
        __syncthreads();   // As ready (kt=0) / previous Bs reads done
        {
            uint4 qa, qb;
            qa.x = pk2(rw[0].x, rw[0].y); qa.y = pk2(rw[0].z, rw[0].w);
            qa.z = pk2(rw[1].x, rw[1].y); qa.w = pk2(rw[1].z, rw[1].w);
            qb.x = pk2(rw[2].x, rw[2].y); qb.y = pk2(rw[2].z, rw[2].w);
            qb.z = pk2(rw[3].x, rw[3].y); qb.w = pk2(rw[3].z, rw[3].w);
            *(uint4*)&Bs[brow][bkh] = qa;
            *(uint4*)&Bs[brow][bkh + 8] = qb;
            qa.x = pk2(rw[4].x, rw[4].y); qa.y = pk2(rw[4].z, rw[4].w);
            qa.z = pk2(rw[5].x, rw[5].y); qa.w = pk2(rw[5].z, rw[5].w);
            qb.x = pk2(rw[6].x, rw[6].y); qb.y = pk2(rw[6].z, rw[6].w);
            qb.z = pk2(rw[7].x, rw[7].y); qb.w = pk2(rw[7].z, rw[7].w);
            *(uint4*)&Bs[brow][bkh + 16] = qa;
            *(uint4*)&Bs[brow][bkh + 24] = qb;
        }
        if (kt < 3) {
            const float* wg2 = wgp + (kt + 1) * 64;
            #pragma unroll
            for (int j = 0; j < 8; ++j) rw[j] = ((const float4*)wg2)[j];
        }
        __syncthreads();

        #pragma unroll
        for (int kk = 0; kk < 2; ++kk) {
            short8 af[2], bf[2];
            #pragma unroll
            for (int mi = 0; mi < 2; ++mi) {
                int row = mi * 16 + l15;
                int c = kt * 8 + kk * 4 + quad;       // logical 8-ch chunk
                af[mi] = *(const short8*)&As[row * 256 + ((c ^ sw) << 3)];
            }
            #pragma unroll
            for (int nj = 0; nj < 2; ++nj)
                bf[nj] = *(const short8*)&Bs[w * 32 + nj * 16 + l15][kk * 32 + quad * 8];
            #pragma unroll
            for (int mi = 0; mi < 2; ++mi)
                #pragma unroll
                for (int nj = 0; nj < 2; ++nj)
                    acc[mi][nj] = __builtin_amdgcn_mfma_f32_16x16x32_bf16(
                        af[mi], bf[nj], acc[mi][nj], 0, 0, 0);
        }
    }

    u16* Yb = Y + (size_t)b * HWD * CD;
    float bias[2];
    #pragma unroll
    for (int nj = 0; nj < 2; ++nj)
        bias[nj] = Bi[n0 + w * 32 + nj * 16 + l15];
    #pragma unroll
    for (int mi = 0; mi < 2; ++mi) {
        #pragma unroll
        for (int r = 0; r < 4; ++r) {
            int p = p0 + mi * 16 + quad * 4 + r;
            #pragma unroll
            for (int nj = 0; nj < 2; ++nj) {
                int ch = n0 + w * 32 + nj * 16 + l15;
                Yb[(size_t)p * CD + ch] = f2b(acc[mi][nj][r] + bias[nj]);
            }
        }
    }
}

// ---------------------------------------------------------------------------
// depthwise 3x3 SAME + bias; q scaled 0.125*log2(e). 2 output rows per block
// with rotating 3-row register window. grid 776: bid<768 = conv work;
// bid>=768 = one-time ow fp32->bf16 pre-pack (8 blocks, feeds out_gemm).
// ---------------------------------------------------------------------------
#define LOADROW(r, hh)                                                      \
    if ((hh) < 0 || (hh) >= 64) {                                           \
        _Pragma("unroll") for (int j = 0; j < 18; ++j) r[j] = 0.f;          \
    } else {                                                                \
        const u16* rp = inb + (size_t)((hh) * 64) * CD;                     \
        r[0] = (w0 > 0) ? b2f(rp[(size_t)(w0 - 1) * CD]) : 0.f;             \
        _Pragma("unroll") for (int j = 1; j <= 16; ++j)                     \
            r[j] = b2f(rp[(size_t)(w0 - 1 + j) * CD]);                      \
        r[17] = (w0 < 48) ? b2f(rp[(size_t)(w0 + 16) * CD]) : 0.f;          \
    }

#define CONVROW(hh, ra, rb, rc)                                             \
    {                                                                       \
        float accv[16];                                                     \
        _Pragma("unroll") for (int pi = 0; pi < 16; ++pi)                   \
            accv[pi] = bias                                                 \
              + w9[0] * ra[pi] + w9[1] * ra[pi + 1] + w9[2] * ra[pi + 2]    \
              + w9[3] * rb[pi] + w9[4] * rb[pi + 1] + w9[5] * rb[pi + 2]    \
              + w9[6] * rc[pi] + w9[7] * rc[pi + 1] + w9[8] * rc[pi + 2];   \
        int p0 = (hh) * 64 + w0;                                            \
        if (which == 2) {                                                   \
            u32 w8[8];                                                      \
            _Pragma("unroll") for (int j = 0; j < 8; ++j)                   \
                w8[j] = pk2(accv[2 * j], accv[2 * j + 1]);                  \
            uint4* dst = (uint4*)(Vt + ((size_t)(b * CD + c)) * HWD + p0);  \
            dst[0] = make_uint4(w8[0], w8[1], w8[2], w8[3]);                \
            dst[1] = make_uint4(w8[4], w8[5], w8[6], w8[7]);                \
        } else {                                                            \
            u16* outp = ((which == 0) ? Q : K) + (size_t)b * HWD * CD;      \
            _Pragma("unroll") for (int pi = 0; pi < 16; ++pi)               \
                outp[(size_t)(p0 + pi) * CD + c] = f2b(accv[pi] * oscale);  \
        }                                                                   \
    }

__global__ __launch_bounds__(256) void dwconv_nc(
    const u16* __restrict__ q1, const u16* __restrict__ k1, const u16* __restrict__ v1,
    const float* __restrict__ qw2, const float* __restrict__ qb2,
    const float* __restrict__ kw2, const float* __restrict__ kb2,
    const float* __restrict__ vw2, const float* __restrict__ vb2,
    const float* __restrict__ ow, u16* __restrict__ wbf,
    u16* __restrict__ Q, u16* __restrict__ K, u16* __restrict__ Vt)
{
    int bid = blockIdx.x;
    int tid = threadIdx.x;

    if (bid >= 768) {
        // ow pre-pack: 8 blocks x 256 thr x 32 = 65536 elems
        int base = (bid - 768) * 8192 + tid * 32;
        const float* s = ow + base;
        u16* d = wbf + base;
        #pragma unroll
        for (int j = 0; j < 4; ++j) {
            float4 a = ((const float4*)s)[2 * j];
            float4 b = ((const float4*)s)[2 * j + 1];
            uint4 o;
            o.x = pk2(a.x, a.y); o.y = pk2(a.z, a.w);
            o.z = pk2(b.x, b.y); o.w = pk2(b.z, b.w);
            ((uint4*)d)[j] = o;
        }
        return;
    }

    int which = bid >> 8;            // 0..2
    int rem = bid & 255;
    int b = rem >> 7;                // batch
    int hp = (rem >> 2) & 31;        // h-pair -> rows 2*hp, 2*hp+1
    int ws = rem & 3;                // w strip
    int h0 = hp * 2, w0 = ws * 16;   // wave-uniform

    const u16* in = ((which == 0) ? q1 : (which == 1) ? k1 : v1) + (size_t)b * HWD * CD;
    const float* wsrc = (which == 0) ? qw2 : (which == 1) ? kw2 : vw2;
    const float* bsrc = (which == 0) ? qb2 : (which == 1) ? kb2 : vb2;
    float oscale = (which == 0) ? 0.18033688011112042f : 1.0f;

    int c = tid;
    float w9[9];
    #pragma unroll
    for (int j = 0; j < 9; ++j) w9[j] = wsrc[c * 9 + j];
    float bias = bsrc[c];

    const u16* inb = in + c;

    float r0[18], r1[18], r2[18];
    LOADROW(r0, h0 - 1)
    LOADROW(r1, h0)
    LOADROW(r2, h0 + 1)
    CONVROW(h0, r0, r1, r2)
    LOADROW(r0, h0 + 2)
    CONVROW(h0 + 1, r1, r2, r0)
}

// ---------------------------------------------------------------------------
// Flash attention, 32x32x16 MFMA, P fully in registers, 2 q-tiles per wave
// (64 q-rows): halved LDS intensity vs 1-qtile (conflicts 4.2M->2.1M, r11).
// Register-bound at ~180 unified VGPR/wave -> 2 blocks/CU = 8 waves; ks=4
// is optimal for this structure. Best measured 44.6 us (r11).
// grid (16,8,4), bounds(256,2), LDS 32 KB. UNCHANGED from r16.
// ---------------------------------------------------------------------------
__global__ __launch_bounds__(256, 2) void attn_kernel(
    const u16* __restrict__ Q, const u16* __restrict__ K,
    const u16* __restrict__ Vt, u16* __restrict__ Opart,
    float* __restrict__ Psum)
{
    int qt = blockIdx.x;
    int bh = blockIdx.y;
    int ks = blockIdx.z;
    int b = bh >> 2, nh = bh & 3;

    __shared__ u16 Ks_[2][64 * 64];   // [key][d], granule-swizzled
    __shared__ u16 Vs_[2][64 * 64];   // [d][key], granule-swizzled

    int tid = threadIdx.x;
    int lane = tid & 63, w = tid >> 6;
    int l31 = lane & 31, h = lane >> 5;
    int sw = l31 & 7;

    const u16* Qb = Q + ((size_t)b * HWD) * CD + nh * 64;
    const u16* Kb = K + ((size_t)b * HWD) * CD + nh * 64;
    const u16* Vb = Vt + ((size_t)bh * HDD) * HWD;

    int q0 = qt * 256 + w * 64;

    // Q fragments (B operand of S^T): lane l31 = qrow, k-slice si, half h
    short8 qf[2][4];
    #pragma unroll
    for (int qi = 0; qi < 2; ++qi)
        #pragma unroll
        for (int si = 0; si < 4; ++si)
            qf[qi][si] = *(const short8*)(Qb +
                (size_t)(q0 + qi * 32 + l31) * CD + si * 16 + h * 8);

    int rr = lane >> 3;
    int gseg = (lane & 7) ^ rr;
    const u16* kgb = Kb + (size_t)(ks * 1024 + w * 16 + rr) * CD + gseg * 8;
    const u16* vgb = Vb + (size_t)(w * 16 + rr) * HWD + ks * 1024 + gseg * 8;

    f32x16 acc[2][2];
    #pragma unroll
    for (int qi = 0; qi < 2; ++qi)
        #pragma unroll
        for (int db = 0; db < 2; ++db)
            #pragma unroll
            for (int r = 0; r < 16; ++r) acc[qi][db][r] = 0.f;
    float psum[2] = {0.f, 0.f};

    // prefetch tile 0 into buf 0
    #pragma unroll
    for (int j = 0; j < 2; ++j) {
        async16(kgb + (size_t)(j * 8) * CD, &Ks_[0][(w * 16 + j * 8) * 64]);
        async16(vgb + (size_t)(j * 8) * HWD, &Vs_[0][(w * 16 + j * 8) * 64]);
    }

    for (int it = 0; it < 16; ++it) {
        int cur = it & 1;
        __syncthreads();   // DMA for tile it drained; buf cur free of readers
        if (it + 1 < 16) {
            int nxt = cur ^ 1;
            #pragma unroll
            for (int j = 0; j < 2; ++j) {
                async16(kgb + (size_t)((it + 1) * 64 + j * 8) * CD,
                        &Ks_[nxt][(w * 16 + j * 8) * 64]);
                async16(vgb + (size_t)(j * 8) * HWD + (it + 1) * 64,
                        &Vs_[nxt][(w * 16 + j * 8) * 64]);
            }
        }

        #pragma unroll
        for (int kb = 0; kb < 2; ++kb) {
            // ---- K fragments (A operand): lane l31 = key row kb*32+l31 ----
            short8 kf[4];
            #pragma unroll
            for (int si = 0; si < 4; ++si)
                kf[si] = *(const short8*)&Ks_[cur][(kb * 32 + l31) * 64 +
                                                   (((si * 2 + h) ^ sw) << 3)];
            // ---- V fragments (B operand): lane l31 = d col ----
            short8 vf[4];   // vf[db*2+z]
            #pragma unroll
            for (int dz = 0; dz < 4; ++dz)
                vf[dz] = *(const short8*)&Vs_[cur][((dz >> 1) * 32 + l31) * 64 +
                             ((((kb * 2 + (dz & 1)) * 2 + h) ^ sw) << 3)];

            #pragma unroll
            for (int qi = 0; qi < 2; ++qi) {
                // ---- S^T tile: col=l31=q, key=(r&3)+8*(r>>2)+4h ----
                f32x16 st;
                #pragma unroll
                for (int r = 0; r < 16; ++r) st[r] = 0.f;
                __builtin_amdgcn_s_setprio(1);
                #pragma unroll
                for (int si = 0; si < 4; ++si)
                    st = __builtin_amdgcn_mfma_f32_32x32x16_bf16(
                        kf[si], qf[qi][si], st, 0, 0, 0);
                __builtin_amdgcn_s_setprio(0);

                // ---- exp2 + row-sum ----
                float e[16];
                #pragma unroll
                for (int r = 0; r < 16; ++r) e[r] = fexp2(st[r]);
                #pragma unroll
                for (int r = 0; r < 16; r += 4)
                    psum[qi] += (e[r] + e[r + 1]) + (e[r + 2] + e[r + 3]);

                // ---- pack to bf16 + permlane re-layout -> PV A fragments ----
                u32 wv[8];
                #pragma unroll
                for (int m = 0; m < 8; ++m) wv[m] = cvtpk(e[2 * m], e[2 * m + 1]);
                u32x2 s02 = plswap(wv[0], wv[2]);
                u32x2 s13 = plswap(wv[1], wv[3]);
                u32x2 s46 = plswap(wv[4], wv[6]);
                u32x2 s57 = plswap(wv[5], wv[7]);
                union { u32 u[4]; short8 s8; } p0_, p1_;
                p0_.u[0] = s02.x; p0_.u[1] = s13.x; p0_.u[2] = s02.y; p0_.u[3] = s13.y;
                p1_.u[0] = s46.x; p1_.u[1] = s57.x; p1_.u[2] = s46.y; p1_.u[3] = s57.y;

                // ---- O += P V ----
                __builtin_amdgcn_s_setprio(1);
                acc[qi][0] = __builtin_amdgcn_mfma_f32_32x32x16_bf16(
                    p0_.s8, vf[0], acc[qi][0], 0, 0, 0);
                acc[qi][0] = __builtin_amdgcn_mfma_f32_32x32x16_bf16(
                    p1_.s8, vf[1], acc[qi][0], 0, 0, 0);
                acc[qi][1] = __builtin_amdgcn_mfma_f32_32x32x16_bf16(
                    p0_.s8, vf[2], acc[qi][1], 0, 0, 0);
                acc[qi][1] = __builtin_amdgcn_mfma_f32_32x32x16_bf16(
                    p1_.s8, vf[3], acc[qi][1], 0, 0, 0);
                __builtin_amdgcn_s_setprio(0);
            }
        }
    }

    // ---- write bf16 partials: O[q = q0+qi*32+(r&3)+8*(r>>2)+4h][d=db*32+l31]
    u16* Ob = Opart + (((size_t)ks * 8 + bh) * HWD) * HDD;
    #pragma unroll
    for (int qi = 0; qi < 2; ++qi)
        #pragma unroll
        for (int db = 0; db < 2; ++db)
            #pragma unroll
            for (int r = 0; r < 16; ++r) {
                int n = q0 + qi * 32 + (r & 3) + 8 * (r >> 2) + 4 * h;
                Ob[(size_t)n * HDD + db * 32 + l31] = f2b(acc[qi][db][r]);
            }

    float* Pb = Psum + ((size_t)ks * 8 + bh) * HWD + q0;
    #pragma unroll
    for (int qi = 0; qi < 2; ++qi) {
        float s = psum[qi] + __shfl_xor(psum[qi], 32);
        if (lane < 32) Pb[qi * 32 + lane] = s;
    }
}

// ---------------------------------------------------------------------------
// out-proj GEMM + bias + residual, fp32 out; fuses the 4-way key-split
// combine; bf16 pre-packed weights. Tile 64 ch x 32 pos -> grid (128, 4, 2)
// = 1024 blocks = 4/CU. LDS 6 KB. UNCHANGED from r16.
// ---------------------------------------------------------------------------
__global__ __launch_bounds__(256) void out_gemm(
    const u16* __restrict__ Wo, const float* __restrict__ Bi,
    const u16* __restrict__ Opart, const float* __restrict__ Psum,
    const float* __restrict__ residual, float* __restrict__ out)
{
    int b = blockIdx.z;
    int m0 = blockIdx.y * 64;    // channels
    int n0 = blockIdx.x * 32;    // positions

    __shared__ u16 As[64][40];
    __shared__ u16 Bs[32][40];

    int tid = threadIdx.x;
    int lane = tid & 63, w = tid >> 6;
    int wm = w >> 1, wn = w & 1;
    int l15 = lane & 15, quad = lane >> 4;

    f32x4 acc[2];
    #pragma unroll
    for (int mi = 0; mi < 2; ++mi)
        acc[mi] = (f32x4){0.f, 0.f, 0.f, 0.f};

    int arow = tid >> 2, aseg = (tid & 3) * 8;
    const u16* wgp = Wo + (size_t)(m0 + arow) * CD + aseg;
    int brow = tid >> 3, bseg = (tid & 7) * 4;
    int pn = n0 + brow;

    uint4 ra = *(const uint4*)wgp;

    uint2 ro[NSPLIT]; float rinv;
    {
        int c = bseg;
        int bh = b * 4 + (c >> 6), d0 = c & 63;
        float p = 0.f;
        #pragma unroll
        for (int s = 0; s < NSPLIT; ++s) {
            ro[s] = *(const uint2*)&Opart[(((size_t)s * 8 + bh) * HWD + pn) * HDD + d0];
            p += Psum[((size_t)s * 8 + bh) * HWD + pn];
        }
        rinv = 1.f / p;
    }

    for (int kt = 0; kt < 8; ++kt) {
        __syncthreads();
        *(uint4*)&As[arow][aseg] = ra;
        {
            float v[4];
            #pragma unroll
            for (int j = 0; j < 4; ++j) v[j] = 0.f;
            #pragma unroll
            for (int s = 0; s < NSPLIT; ++s) {
                u16 t[4];
                *(uint2*)t = ro[s];
                #pragma unroll
                for (int j = 0; j < 4; ++j) v[j] += b2f(t[j]);
            }
            uint2 bb;
            bb.x = pk2(v[0] * rinv, v[1] * rinv);
            bb.y = pk2(v[2] * rinv, v[3] * rinv);
            *(uint2*)&Bs[brow][bseg] = bb;
        }
        if (kt < 7) {
            ra = *(const uint4*)(wgp + (kt + 1) * 32);
            int c = (kt + 1) * 32 + bseg;
            int bh = b * 4 + (c >> 6), d0 = c & 63;
            float p = 0.f;
            #pragma unroll
            for (int s = 0; s < NSPLIT; ++s) {
                ro[s] = *(const uint2*)&Opart[(((size_t)s * 8 + bh) * HWD + pn) * HDD + d0];
                p += Psum[((size_t)s * 8 + bh) * HWD + pn];
            }
            rinv = 1.f / p;
        }
        __syncthreads();

        short8 af[2], bf;
        #pragma unroll
        for (int mi = 0; mi < 2; ++mi)
            af[mi] = *(const short8*)&As[wm * 32 + mi * 16 + l15][quad * 8];
        bf = *(const short8*)&Bs[wn * 16 + l15][quad * 8];
        #pragma unroll
        for (int mi = 0; mi < 2; ++mi)
            acc[mi] = __builtin_amdgcn_mfma_f32_16x16x32_bf16(
                af[mi], bf, acc[mi], 0, 0, 0);
    }

    #pragma unroll
    for (int mi = 0; mi < 2; ++mi) {
        int mb = m0 + wm * 32 + mi * 16 + quad * 4;
        #pragma unroll
        for (int r = 0; r < 4; ++r) {
            float bias = Bi[mb + r];
            const float* res = residual + (size_t)(b * CD + mb + r) * HWD;
            float* o = out + (size_t)(b * CD + mb + r) * HWD;
            int n = n0 + wn * 16 + l15;
            o[n] = acc[mi][r] + bias + res[n];
        }
    }
}

extern "C" void kernel_launch(void* const* d_in, const int* in_sizes, int n_in,
                              void* d_out, int out_size, void* d_ws, size_t ws_size,
                              hipStream_t stream) {
    (void)in_sizes; (void)n_in; (void)out_size; (void)ws_size;

    const float* image = (const float*)d_in[0];
    const float* guide = (const float*)d_in[1];
    const float* ln1_g = (const float*)d_in[2];
    const float* ln1_b = (const float*)d_in[3];
    const float* ln2_g = (const float*)d_in[4];
    const float* ln2_b = (const float*)d_in[5];
    const float* qw1 = (const float*)d_in[6];
    const float* qb1 = (const float*)d_in[7];
    const float* qw2 = (const float*)d_in[8];
    const float* qb2 = (const float*)d_in[9];
    const float* kw1 = (const float*)d_in[10];
    const float* kb1 = (const float*)d_in[11];
    const float* kw2 = (const float*)d_in[12];
    const float* kb2 = (const float*)d_in[13];
    const float* vw1 = (const float*)d_in[14];
    const float* vb1 = (const float*)d_in[15];
    const float* vw2 = (const float*)d_in[16];
    const float* vb2 = (const float*)d_in[17];
    const float* ow  = (const float*)d_in[18];
    const float* ob  = (const float*)d_in[19];
    float* out = (float*)d_out;

    char* ws = (char*)d_ws;
    u16* q1    = (u16*)(ws + (size_t)8  * (1 << 20));
    u16* k1    = (u16*)(ws + (size_t)12 * (1 << 20));
    u16* v1    = (u16*)(ws + (size_t)16 * (1 << 20));
    u16* Qh    = (u16*)(ws + (size_t)20 * (1 << 20));
    u16* Kh    = (u16*)(ws + (size_t)24 * (1 << 20));
    u16* Vt    = (u16*)(ws + (size_t)28 * (1 << 20));
    // attn partials overlay dead phase-1 buffers (hot in L2: avoids
    // write-allocate RMW fetches); Psum in v1's region.
    u16*   Opart = (u16*)(ws + (size_t)0  * (1 << 20));
    float* Psum  = (float*)(ws + (size_t)18 * (1 << 20));
    // pre-packed bf16 ow (packed by dwconv's extra blocks), 128 KB
    u16*   Wbf   = (u16*)(ws + (size_t)33 * (1 << 20));

    ln_qkv_gemm<<<dim3(2, 128, 6), dim3(256), 0, stream>>>(
        image, guide, ln1_g, ln1_b, ln2_g, ln2_b,
        qw1, kw1, vw1, qb1, kb1, vb1, q1, k1, v1);

    dwconv_nc<<<dim3(776), dim3(256), 0, stream>>>(
        q1, k1, v1, qw2, qb2, kw2, kb2, vw2, vb2, ow, Wbf, Qh, Kh, Vt);

    attn_kernel<<<dim3(16, 8, NSPLIT), dim3(256), 0, stream>>>(Qh, Kh, Vt, Opart, Psum);

    out_gemm<<<dim3(128, 4, 2), dim3(256), 0, stream>>>(
        Wbf, ob, Opart, Psum, image, out);
}

// Round 18
// 173.165 us; speedup vs baseline: 1.0877x; 1.0877x over previous
//
#include <hip/hip_runtime.h>
#include <cstdint>
#include <cstddef>

typedef unsigned short u16;
typedef unsigned int u32;
typedef __attribute__((ext_vector_type(8))) short short8;
typedef __attribute__((ext_vector_type(4))) float f32x4;
typedef __attribute__((ext_vector_type(16))) float f32x16;
typedef __attribute__((ext_vector_type(2))) unsigned int u32x2;

#define CD 256
#define HWD 4096
#define NHD 4
#define HDD 64
#define NSPLIT 4

static __device__ __forceinline__ u16 f2b(float f) {
    u32 u = __builtin_bit_cast(u32, f);
    return (u16)((u + 0x7fffu + ((u >> 16) & 1u)) >> 16);
}
static __device__ __forceinline__ float b2f(u16 h) {
    return __builtin_bit_cast(float, (u32)h << 16);
}
static __device__ __forceinline__ u32 pk2(float a, float b) {
    return (u32)f2b(a) | ((u32)f2b(b) << 16);
}
static __device__ __forceinline__ float fexp2(float x) {
#if __has_builtin(__builtin_amdgcn_exp2f)
    return __builtin_amdgcn_exp2f(x);
#else
    return __expf(x * 0.69314718056f);
#endif
}
// v_cvt_pk_bf16_f32: pack two f32 -> one u32 of 2 bf16 (no builtin on gfx950)
static __device__ __forceinline__ u32 cvtpk(float lo, float hi) {
    u32 r;
    asm("v_cvt_pk_bf16_f32 %0, %1, %2" : "=v"(r) : "v"(lo), "v"(hi));
    return r;
}
// lanes: (a',b') = ([a.lo|b.lo], [a.hi|b.hi])
static __device__ __forceinline__ u32x2 plswap(u32 a, u32 b) {
    return __builtin_amdgcn_permlane32_swap(a, b, false, false);
}
// async global->LDS DMA, 16 B per lane; LDS dest = wave-uniform base + lane*16
static __device__ __forceinline__ void async16(const void* g, void* l) {
    __builtin_amdgcn_global_load_lds(
        (const __attribute__((address_space(1))) unsigned int*)g,
        (__attribute__((address_space(3))) unsigned int*)l,
        16, 0, 0);
}

// ---------------------------------------------------------------------------
// LayerNorm over C + transpose to bf16 [b][p][c]. Single global read pass
// (32 values register-cached, fully unrolled -> no scratch).
// grid 544: bid<512 = LN work; bid>=512 = one-time fp32->bf16 weight pre-pack.
// ---------------------------------------------------------------------------
__global__ __launch_bounds__(256) void ln_transpose(
    const float* __restrict__ x0, const float* __restrict__ x1,
    const float* __restrict__ g0, const float* __restrict__ b0,
    const float* __restrict__ g1, const float* __restrict__ b1,
    const float* __restrict__ qw1, const float* __restrict__ kw1,
    const float* __restrict__ vw1, const float* __restrict__ ow,
    u16* __restrict__ out0, u16* __restrict__ out1, u16* __restrict__ wbf)
{
    int bid = blockIdx.x;
    int tid = threadIdx.x;

    if (bid >= 512) {
        // weight pre-pack: 32 blocks x 256 thr x 32 elems = 4 x 65536
        int base = (bid - 512) * 8192 + tid * 32;
        int which = base >> 16;              // wave-uniform
        int off = base & 65535;
        const float* s = (which == 0) ? qw1 : (which == 1) ? kw1
                       : (which == 2) ? vw1 : ow;
        s += off;
        u16* d = wbf + (size_t)which * 65536 + off;
        #pragma unroll
        for (int j = 0; j < 4; ++j) {
            float4 a = ((const float4*)s)[2 * j];
            float4 b = ((const float4*)s)[2 * j + 1];
            uint4 o;
            o.x = pk2(a.x, a.y); o.y = pk2(a.z, a.w);
            o.z = pk2(b.x, b.y); o.w = pk2(b.z, b.w);
            ((uint4*)d)[j] = o;
        }
        return;
    }

    int t = bid >> 8, b = (bid >> 7) & 1, p0 = (bid & 127) << 5;
    const float* x = t ? x1 : x0;
    const float* g = t ? g1 : g0;
    const float* bb = t ? b1 : b0;
    u16* out = t ? out1 : out0;

    int tx = tid & 31, ty = tid >> 5;   // ty 0..7 = channel slice
    const float* xb = x + (size_t)b * CD * HWD + p0 + tx;

    __shared__ float red[2][8][32];
    __shared__ u16 T[256][33];

    float xv[32];
    float s = 0.f, sq = 0.f;
    #pragma unroll
    for (int i = 0; i < 32; ++i) {
        float v = xb[(size_t)(ty * 32 + i) * HWD];
        xv[i] = v;
        s += v; sq += v * v;
    }
    red[0][ty][tx] = s; red[1][ty][tx] = sq;
    __syncthreads();
    float st = 0.f, sqt = 0.f;
    #pragma unroll
    for (int j = 0; j < 8; ++j) { st += red[0][j][tx]; sqt += red[1][j][tx]; }
    float mean = st * (1.f / 256.f);
    float var = sqt * (1.f / 256.f) - mean * mean;
    float rstd = rsqrtf(var + 1e-5f);

    #pragma unroll
    for (int i = 0; i < 32; ++i) {
        int c = ty * 32 + i;
        float v = (xv[i] - mean) * rstd * g[c] + bb[c];
        T[c][tx] = f2b(v);
    }
    __syncthreads();

    #pragma unroll
    for (int pass = 0; pass < 4; ++pass) {
        int idx = pass * 256 + tid;
        int p = idx >> 5, cs = (idx & 31) * 8;
        u16 tmp[8];
        #pragma unroll
        for (int j = 0; j < 8; ++j) tmp[j] = T[cs + j][p];
        *(uint4*)&out[((size_t)b * HWD + p0 + p) * CD + cs] = *(const uint4*)tmp;
    }
}

// ---------------------------------------------------------------------------
// conv1x1 GEMM, bf16 [p][c] input, bf16 pre-packed weights, BK=64 K-step,
// DMA-staged (global_load_lds width=16) double-buffered LDS: linear dest +
// pre-swizzled global source chunk seg^(row&7), XOR on read.
// Tile 32 pos x 128 ch -> grid (2, 128, 6) = 1536 blocks; LDS 40 KB -> 4/CU.
// ---------------------------------------------------------------------------
__global__ __launch_bounds__(256) void qkv_gemm(
    const u16* __restrict__ xT, const u16* __restrict__ gT,
    const u16* __restrict__ Wbf,
    const float* __restrict__ qb1, const float* __restrict__ kb1,
    const float* __restrict__ vb1,
    u16* __restrict__ q1, u16* __restrict__ k1, u16* __restrict__ v1)
{
    int z = blockIdx.z;
    int mm = z >> 1, b = z & 1;
    const u16* X    = (mm == 0) ? xT : gT;
    const u16* W    = Wbf + (size_t)mm * 65536;
    const float* Bi = (mm == 0) ? qb1 : (mm == 1) ? kb1 : vb1;
    u16* Y          = (mm == 0) ? q1 : (mm == 1) ? k1 : v1;

    int n0 = blockIdx.x * 128;   // channel tile
    int p0 = blockIdx.y * 32;    // position tile

    __shared__ u16 As[2][32 * 64];    // 4 KB per buf, chunk-swizzled
    __shared__ u16 Bs[2][128 * 64];   // 16 KB per buf, chunk-swizzled

    int tid = threadIdx.x;
    int lane = tid & 63, w = tid >> 6;
    int l15 = lane & 15, quad = lane >> 4;
    int sw = l15 & 7;

    // staging: thread (srow, sseg); LDS linear offset == tid*8 u16 per tile
    int srow = tid >> 3;          // 0..31
    int sseg = tid & 7;           // 0..7
    const u16* Xb = X + (size_t)b * HWD * CD;
    const u16* agp = Xb + (size_t)(p0 + srow) * CD + (sseg ^ (srow & 7)) * 8;
    const u16* wgp0 = W + (size_t)(n0 +  0 + srow) * CD + (sseg ^ (srow & 7)) * 8;
    const u16* wgp1 = W + (size_t)(n0 + 32 + srow) * CD + (sseg ^ (srow & 7)) * 8;
    const u16* wgp2 = W + (size_t)(n0 + 64 + srow) * CD + (sseg ^ (srow & 7)) * 8;
    const u16* wgp3 = W + (size_t)(n0 + 96 + srow) * CD + (sseg ^ (srow & 7)) * 8;

    f32x4 acc[2][2];
    #pragma unroll
    for (int mi = 0; mi < 2; ++mi)
        #pragma unroll
        for (int nj = 0; nj < 2; ++nj)
            acc[mi][nj] = (f32x4){0.f, 0.f, 0.f, 0.f};

    // prefetch kt=0 into buf 0 (wave-uniform LDS bases)
    async16(agp, &As[0][w * 512]);
    async16(wgp0, &Bs[0][0 * 2048 + w * 512]);
    async16(wgp1, &Bs[0][1 * 2048 + w * 512]);
    async16(wgp2, &Bs[0][2 * 2048 + w * 512]);
    async16(wgp3, &Bs[0][3 * 2048 + w * 512]);

    for (int kt = 0; kt < 4; ++kt) {
        int cur = kt & 1;
        __syncthreads();   // DMA for buf cur drained; buf nxt free of readers
        if (kt < 3) {
            int nxt = cur ^ 1;
            async16(agp + (kt + 1) * 64, &As[nxt][w * 512]);
            async16(wgp0 + (kt + 1) * 64, &Bs[nxt][0 * 2048 + w * 512]);
            async16(wgp1 + (kt + 1) * 64, &Bs[nxt][1 * 2048 + w * 512]);
            async16(wgp2 + (kt + 1) * 64, &Bs[nxt][2 * 2048 + w * 512]);
            async16(wgp3 + (kt + 1) * 64, &Bs[nxt][3 * 2048 + w * 512]);
        }

        #pragma unroll
        for (int kk = 0; kk < 2; ++kk) {
            short8 af[2], bf[2];
            #pragma unroll
            for (int mi = 0; mi < 2; ++mi) {
                int row = mi * 16 + l15;
                af[mi] = *(const short8*)&As[cur][row * 64 +
                                                  (((kk * 4 + quad) ^ sw) << 3)];
            }
            #pragma unroll
            for (int nj = 0; nj < 2; ++nj) {
                int row = w * 32 + nj * 16 + l15;
                bf[nj] = *(const short8*)&Bs[cur][row * 64 +
                                                  (((kk * 4 + quad) ^ sw) << 3)];
            }
            #pragma unroll
            for (int mi = 0; mi < 2; ++mi)
                #pragma unroll
                for (int nj = 0; nj < 2; ++nj)
                    acc[mi][nj] = __builtin_amdgcn_mfma_f32_16x16x32_bf16(
                        af[mi], bf[nj], acc[mi][nj], 0, 0, 0);
        }
    }

    u16* Yb = Y + (size_t)b * HWD * CD;
    float bias[2];
    #pragma unroll
    for (int nj = 0; nj < 2; ++nj)
        bias[nj] = Bi[n0 + w * 32 + nj * 16 + l15];
    #pragma unroll
    for (int mi = 0; mi < 2; ++mi) {
        #pragma unroll
        for (int r = 0; r < 4; ++r) {
            int p = p0 + mi * 16 + quad * 4 + r;
            #pragma unroll
            for (int nj = 0; nj < 2; ++nj) {
                int ch = n0 + w * 32 + nj * 16 + l15;
                Yb[(size_t)p * CD + ch] = f2b(acc[mi][nj][r] + bias[nj]);
            }
        }
    }
}

// ---------------------------------------------------------------------------
// depthwise 3x3 SAME + bias; q scaled 0.125*log2(e). 2 output rows per block
// with rotating 3-row register window (2x input reads instead of 3x).
// grid 768; block 256 (lane = channel).
// ---------------------------------------------------------------------------
#define LOADROW(r, hh)                                                      \
    if ((hh) < 0 || (hh) >= 64) {                                           \
        _Pragma("unroll") for (int j = 0; j < 18; ++j) r[j] = 0.f;          \
    } else {                                                                \
        const u16* rp = inb + (size_t)((hh) * 64) * CD;                     \
        r[0] = (w0 > 0) ? b2f(rp[(size_t)(w0 - 1) * CD]) : 0.f;             \
        _Pragma("unroll") for (int j = 1; j <= 16; ++j)                     \
            r[j] = b2f(rp[(size_t)(w0 - 1 + j) * CD]);                      \
        r[17] = (w0 < 48) ? b2f(rp[(size_t)(w0 + 16) * CD]) : 0.f;          \
    }

#define CONVROW(hh, ra, rb, rc)                                             \
    {                                                                       \
        float accv[16];                                                     \
        _Pragma("unroll") for (int pi = 0; pi < 16; ++pi)                   \
            accv[pi] = bias                                                 \
              + w9[0] * ra[pi] + w9[1] * ra[pi + 1] + w9[2] * ra[pi + 2]    \
              + w9[3] * rb[pi] + w9[4] * rb[pi + 1] + w9[5] * rb[pi + 2]    \
              + w9[6] * rc[pi] + w9[7] * rc[pi + 1] + w9[8] * rc[pi + 2];   \
        int p0 = (hh) * 64 + w0;                                            \
        if (which == 2) {                                                   \
            u32 w8[8];                                                      \
            _Pragma("unroll") for (int j = 0; j < 8; ++j)                   \
                w8[j] = pk2(accv[2 * j], accv[2 * j + 1]);                  \
            uint4* dst = (uint4*)(Vt + ((size_t)(b * CD + c)) * HWD + p0);  \
            dst[0] = make_uint4(w8[0], w8[1], w8[2], w8[3]);                \
            dst[1] = make_uint4(w8[4], w8[5], w8[6], w8[7]);                \
        } else {                                                            \
            u16* outp = ((which == 0) ? Q : K) + (size_t)b * HWD * CD;      \
            _Pragma("unroll") for (int pi = 0; pi < 16; ++pi)               \
                outp[(size_t)(p0 + pi) * CD + c] = f2b(accv[pi] * oscale);  \
        }                                                                   \
    }

__global__ __launch_bounds__(256) void dwconv_nc(
    const u16* __restrict__ q1, const u16* __restrict__ k1, const u16* __restrict__ v1,
    const float* __restrict__ qw2, const float* __restrict__ qb2,
    const float* __restrict__ kw2, const float* __restrict__ kb2,
    const float* __restrict__ vw2, const float* __restrict__ vb2,
    u16* __restrict__ Q, u16* __restrict__ K, u16* __restrict__ Vt)
{
    int bid = blockIdx.x;
    int which = bid >> 8;            // 0..2
    int rem = bid & 255;
    int b = rem >> 7;                // batch
    int hp = (rem >> 2) & 31;        // h-pair -> rows 2*hp, 2*hp+1
    int ws = rem & 3;                // w strip
    int h0 = hp * 2, w0 = ws * 16;   // wave-uniform

    const u16* in = ((which == 0) ? q1 : (which == 1) ? k1 : v1) + (size_t)b * HWD * CD;
    const float* wsrc = (which == 0) ? qw2 : (which == 1) ? kw2 : vw2;
    const float* bsrc = (which == 0) ? qb2 : (which == 1) ? kb2 : vb2;
    float oscale = (which == 0) ? 0.18033688011112042f : 1.0f;

    int c = threadIdx.x;
    float w9[9];
    #pragma unroll
    for (int j = 0; j < 9; ++j) w9[j] = wsrc[c * 9 + j];
    float bias = bsrc[c];

    const u16* inb = in + c;

    float r0[18], r1[18], r2[18];
    LOADROW(r0, h0 - 1)
    LOADROW(r1, h0)
    LOADROW(r2, h0 + 1)
    CONVROW(h0, r0, r1, r2)
    LOADROW(r0, h0 + 2)
    CONVROW(h0 + 1, r1, r2, r0)
}

// ---------------------------------------------------------------------------
// Flash attention, 32x32x16 MFMA, P fully in registers, 2 q-tiles per wave
// (64 q-rows): halved LDS intensity vs 1-qtile (conflicts 4.2M->2.1M, r11).
// Register-bound at ~180 unified VGPR/wave -> 2 blocks/CU = 8 waves; ks=4
// is optimal for this structure. Best measured 44.6 us (r11).
// grid (16,8,4), bounds(256,2), LDS 32 KB.
// ---------------------------------------------------------------------------
__global__ __launch_bounds__(256, 2) void attn_kernel(
    const u16* __restrict__ Q, const u16* __restrict__ K,
    const u16* __restrict__ Vt, u16* __restrict__ Opart,
    float* __restrict__ Psum)
{
    int qt = blockIdx.x;
    int bh = blockIdx.y;
    int ks = blockIdx.z;
    int b = bh >> 2, nh = bh & 3;

    __shared__ u16 Ks_[2][64 * 64];   // [key][d], granule-swizzled
    __shared__ u16 Vs_[2][64 * 64];   // [d][key], granule-swizzled

    int tid = threadIdx.x;
    int lane = tid & 63, w = tid >> 6;
    int l31 = lane & 31, h = lane >> 5;
    int sw = l31 & 7;

    const u16* Qb = Q + ((size_t)b * HWD) * CD + nh * 64;
    const u16* Kb = K + ((size_t)b * HWD) * CD + nh * 64;
    const u16* Vb = Vt + ((size_t)bh * HDD) * HWD;

    int q0 = qt * 256 + w * 64;

    // Q fragments (B operand of S^T): lane l31 = qrow, k-slice si, half h
    short8 qf[2][4];
    #pragma unroll
    for (int qi = 0; qi < 2; ++qi)
        #pragma unroll
        for (int si = 0; si < 4; ++si)
            qf[qi][si] = *(const short8*)(Qb +
                (size_t)(q0 + qi * 32 + l31) * CD + si * 16 + h * 8);

    int rr = lane >> 3;
    int gseg = (lane & 7) ^ rr;
    const u16* kgb = Kb + (size_t)(ks * 1024 + w * 16 + rr) * CD + gseg * 8;
    const u16* vgb = Vb + (size_t)(w * 16 + rr) * HWD + ks * 1024 + gseg * 8;

    f32x16 acc[2][2];
    #pragma unroll
    for (int qi = 0; qi < 2; ++qi)
        #pragma unroll
        for (int db = 0; db < 2; ++db)
            #pragma unroll
            for (int r = 0; r < 16; ++r) acc[qi][db][r] = 0.f;
    float psum[2] = {0.f, 0.f};

    // prefetch tile 0 into buf 0
    #pragma unroll
    for (int j = 0; j < 2; ++j) {
        async16(kgb + (size_t)(j * 8) * CD, &Ks_[0][(w * 16 + j * 8) * 64]);
        async16(vgb + (size_t)(j * 8) * HWD, &Vs_[0][(w * 16 + j * 8) * 64]);
    }

    for (int it = 0; it < 16; ++it) {
        int cur = it & 1;
        __syncthreads();   // DMA for tile it drained; buf cur free of readers
        if (it + 1 < 16) {
            int nxt = cur ^ 1;
            #pragma unroll
            for (int j = 0; j < 2; ++j) {
                async16(kgb + (size_t)((it + 1) * 64 + j * 8) * CD,
                        &Ks_[nxt][(w * 16 + j * 8) * 64]);
                async16(vgb + (size_t)(j * 8) * HWD + (it + 1) * 64,
                        &Vs_[nxt][(w * 16 + j * 8) * 64]);
            }
        }

        #pragma unroll
        for (int kb = 0; kb < 2; ++kb) {
            // ---- K fragments (A operand): lane l31 = key row kb*32+l31 ----
            short8 kf[4];
            #pragma unroll
            for (int si = 0; si < 4; ++si)
                kf[si] = *(const short8*)&Ks_[cur][(kb * 32 + l31) * 64 +
                                                   (((si * 2 + h) ^ sw) << 3)];
            // ---- V fragments (B operand): lane l31 = d col ----
            short8 vf[4];   // vf[db*2+z]
            #pragma unroll
            for (int dz = 0; dz < 4; ++dz)
                vf[dz] = *(const short8*)&Vs_[cur][((dz >> 1) * 32 + l31) * 64 +
                             ((((kb * 2 + (dz & 1)) * 2 + h) ^ sw) << 3)];

            #pragma unroll
            for (int qi = 0; qi < 2; ++qi) {
                // ---- S^T tile: col=l31=q, key=(r&3)+8*(r>>2)+4h ----
                f32x16 st;
                #pragma unroll
                for (int r = 0; r < 16; ++r) st[r] = 0.f;
                __builtin_amdgcn_s_setprio(1);
                #pragma unroll
                for (int si = 0; si < 4; ++si)
                    st = __builtin_amdgcn_mfma_f32_32x32x16_bf16(
                        kf[si], qf[qi][si], st, 0, 0, 0);
                __builtin_amdgcn_s_setprio(0);

                // ---- exp2 + row-sum ----
                float e[16];
                #pragma unroll
                for (int r = 0; r < 16; ++r) e[r] = fexp2(st[r]);
                #pragma unroll
                for (int r = 0; r < 16; r += 4)
                    psum[qi] += (e[r] + e[r + 1]) + (e[r + 2] + e[r + 3]);

                // ---- pack to bf16 + permlane re-layout -> PV A fragments ----
                u32 wv[8];
                #pragma unroll
                for (int m = 0; m < 8; ++m) wv[m] = cvtpk(e[2 * m], e[2 * m + 1]);
                u32x2 s02 = plswap(wv[0], wv[2]);
                u32x2 s13 = plswap(wv[1], wv[3]);
                u32x2 s46 = plswap(wv[4], wv[6]);
                u32x2 s57 = plswap(wv[5], wv[7]);
                union { u32 u[4]; short8 s8; } p0_, p1_;
                p0_.u[0] = s02.x; p0_.u[1] = s13.x; p0_.u[2] = s02.y; p0_.u[3] = s13.y;
                p1_.u[0] = s46.x; p1_.u[1] = s57.x; p1_.u[2] = s46.y; p1_.u[3] = s57.y;

                // ---- O += P V ----
                __builtin_amdgcn_s_setprio(1);
                acc[qi][0] = __builtin_amdgcn_mfma_f32_32x32x16_bf16(
                    p0_.s8, vf[0], acc[qi][0], 0, 0, 0);
                acc[qi][0] = __builtin_amdgcn_mfma_f32_32x32x16_bf16(
                    p1_.s8, vf[1], acc[qi][0], 0, 0, 0);
                acc[qi][1] = __builtin_amdgcn_mfma_f32_32x32x16_bf16(
                    p0_.s8, vf[2], acc[qi][1], 0, 0, 0);
                acc[qi][1] = __builtin_amdgcn_mfma_f32_32x32x16_bf16(
                    p1_.s8, vf[3], acc[qi][1], 0, 0, 0);
                __builtin_amdgcn_s_setprio(0);
            }
        }
    }

    // ---- write bf16 partials: O[q = q0+qi*32+(r&3)+8*(r>>2)+4h][d=db*32+l31]
    u16* Ob = Opart + (((size_t)ks * 8 + bh) * HWD) * HDD;
    #pragma unroll
    for (int qi = 0; qi < 2; ++qi)
        #pragma unroll
        for (int db = 0; db < 2; ++db)
            #pragma unroll
            for (int r = 0; r < 16; ++r) {
                int n = q0 + qi * 32 + (r & 3) + 8 * (r >> 2) + 4 * h;
                Ob[(size_t)n * HDD + db * 32 + l31] = f2b(acc[qi][db][r]);
            }

    float* Pb = Psum + ((size_t)ks * 8 + bh) * HWD + q0;
    #pragma unroll
    for (int qi = 0; qi < 2; ++qi) {
        float s = psum[qi] + __shfl_xor(psum[qi], 32);
        if (lane < 32) Pb[qi * 32 + lane] = s;
    }
}

// ---------------------------------------------------------------------------
// out-proj GEMM + bias + residual, fp32 out; fuses the 4-way key-split
// combine; bf16 pre-packed weights. Tile 64 ch x 32 pos -> grid (128, 4, 2)
// = 1024 blocks = 4/CU. LDS 6 KB.
// ---------------------------------------------------------------------------
__global__ __launch_bounds__(256) void out_gemm(
    const u16* __restrict__ Wo, const float* __restrict__ Bi,
    const u16* __restrict__ Opart, const float* __restrict__ Psum,
    const float* __restrict__ residual, float* __restrict__ out)
{
    int b = blockIdx.z;
    int m0 = blockIdx.y * 64;    // channels
    int n0 = blockIdx.x * 32;    // positions

    __shared__ u16 As[64][40];
    __shared__ u16 Bs[32][40];

    int tid = threadIdx.x;
    int lane = tid & 63, w = tid >> 6;
    int wm = w >> 1, wn = w & 1;
    int l15 = lane & 15, quad = lane >> 4;

    f32x4 acc[2];
    #pragma unroll
    for (int mi = 0; mi < 2; ++mi)
        acc[mi] = (f32x4){0.f, 0.f, 0.f, 0.f};

    int arow = tid >> 2, aseg = (tid & 3) * 8;
    const u16* wgp = Wo + (size_t)(m0 + arow) * CD + aseg;
    int brow = tid >> 3, bseg = (tid & 7) * 4;
    int pn = n0 + brow;

    uint4 ra = *(const uint4*)wgp;

    uint2 ro[NSPLIT]; float rinv;
    {
        int c = bseg;
        int bh = b * 4 + (c >> 6), d0 = c & 63;
        float p = 0.f;
        #pragma unroll
        for (int s = 0; s < NSPLIT; ++s) {
            ro[s] = *(const uint2*)&Opart[(((size_t)s * 8 + bh) * HWD + pn) * HDD + d0];
            p += Psum[((size_t)s * 8 + bh) * HWD + pn];
        }
        rinv = 1.f / p;
    }

    for (int kt = 0; kt < 8; ++kt) {
        __syncthreads();
        *(uint4*)&As[arow][aseg] = ra;
        {
            float v[4];
            #pragma unroll
            for (int j = 0; j < 4; ++j) v[j] = 0.f;
            #pragma unroll
            for (int s = 0; s < NSPLIT; ++s) {
                u16 t[4];
                *(uint2*)t = ro[s];
                #pragma unroll
                for (int j = 0; j < 4; ++j) v[j] += b2f(t[j]);
            }
            uint2 bb;
            bb.x = pk2(v[0] * rinv, v[1] * rinv);
            bb.y = pk2(v[2] * rinv, v[3] * rinv);
            *(uint2*)&Bs[brow][bseg] = bb;
        }
        if (kt < 7) {
            ra = *(const uint4*)(wgp + (kt + 1) * 32);
            int c = (kt + 1) * 32 + bseg;
            int bh = b * 4 + (c >> 6), d0 = c & 63;
            float p = 0.f;
            #pragma unroll
            for (int s = 0; s < NSPLIT; ++s) {
                ro[s] = *(const uint2*)&Opart[(((size_t)s * 8 + bh) * HWD + pn) * HDD + d0];
                p += Psum[((size_t)s * 8 + bh) * HWD + pn];
            }
            rinv = 1.f / p;
        }
        __syncthreads();

        short8 af[2], bf;
        #pragma unroll
        for (int mi = 0; mi < 2; ++mi)
            af[mi] = *(const short8*)&As[wm * 32 + mi * 16 + l15][quad * 8];
        bf = *(const short8*)&Bs[wn * 16 + l15][quad * 8];
        #pragma unroll
        for (int mi = 0; mi < 2; ++mi)
            acc[mi] = __builtin_amdgcn_mfma_f32_16x16x32_bf16(
                af[mi], bf, acc[mi], 0, 0, 0);
    }

    #pragma unroll
    for (int mi = 0; mi < 2; ++mi) {
        int mb = m0 + wm * 32 + mi * 16 + quad * 4;
        #pragma unroll
        for (int r = 0; r < 4; ++r) {
            float bias = Bi[mb + r];
            const float* res = residual + (size_t)(b * CD + mb + r) * HWD;
            float* o = out + (size_t)(b * CD + mb + r) * HWD;
            int n = n0 + wn * 16 + l15;
            o[n] = acc[mi][r] + bias + res[n];
        }
    }
}

extern "C" void kernel_launch(void* const* d_in, const int* in_sizes, int n_in,
                              void* d_out, int out_size, void* d_ws, size_t ws_size,
                              hipStream_t stream) {
    (void)in_sizes; (void)n_in; (void)out_size; (void)ws_size;

    const float* image = (const float*)d_in[0];
    const float* guide = (const float*)d_in[1];
    const float* ln1_g = (const float*)d_in[2];
    const float* ln1_b = (const float*)d_in[3];
    const float* ln2_g = (const float*)d_in[4];
    const float* ln2_b = (const float*)d_in[5];
    const float* qw1 = (const float*)d_in[6];
    const float* qb1 = (const float*)d_in[7];
    const float* qw2 = (const float*)d_in[8];
    const float* qb2 = (const float*)d_in[9];
    const float* kw1 = (const float*)d_in[10];
    const float* kb1 = (const float*)d_in[11];
    const float* kw2 = (const float*)d_in[12];
    const float* kb2 = (const float*)d_in[13];
    const float* vw1 = (const float*)d_in[14];
    const float* vb1 = (const float*)d_in[15];
    const float* vw2 = (const float*)d_in[16];
    const float* vb2 = (const float*)d_in[17];
    const float* ow  = (const float*)d_in[18];
    const float* ob  = (const float*)d_in[19];
    float* out = (float*)d_out;

    char* ws = (char*)d_ws;
    u16* xT    = (u16*)(ws + (size_t)0  * (1 << 20));
    u16* gT    = (u16*)(ws + (size_t)4  * (1 << 20));
    u16* q1    = (u16*)(ws + (size_t)8  * (1 << 20));
    u16* k1    = (u16*)(ws + (size_t)12 * (1 << 20));
    u16* v1    = (u16*)(ws + (size_t)16 * (1 << 20));
    u16* Qh    = (u16*)(ws + (size_t)20 * (1 << 20));
    u16* Kh    = (u16*)(ws + (size_t)24 * (1 << 20));
    u16* Vt    = (u16*)(ws + (size_t)28 * (1 << 20));
    // attn partials overlay dead phase-1 buffers (hot in L2: avoids
    // write-allocate RMW fetches); Psum in v1's region.
    u16*   Opart = (u16*)(ws + (size_t)0  * (1 << 20));
    float* Psum  = (float*)(ws + (size_t)18 * (1 << 20));
    // pre-packed bf16 weights [qw1|kw1|vw1|ow], 512 KB
    u16*   Wbf   = (u16*)(ws + (size_t)33 * (1 << 20));

    ln_transpose<<<dim3(544), dim3(256), 0, stream>>>(
        image, guide, ln1_g, ln1_b, ln2_g, ln2_b,
        qw1, kw1, vw1, ow, xT, gT, Wbf);

    qkv_gemm<<<dim3(2, 128, 6), dim3(256), 0, stream>>>(
        xT, gT, Wbf, qb1, kb1, vb1, q1, k1, v1);

    dwconv_nc<<<dim3(768), dim3(256), 0, stream>>>(
        q1, k1, v1, qw2, qb2, kw2, kb2, vw2, vb2, Qh, Kh, Vt);

    attn_kernel<<<dim3(16, 8, NSPLIT), dim3(256), 0, stream>>>(Qh, Kh, Vt, Opart, Psum);

    out_gemm<<<dim3(128, 4, 2), dim3(256), 0, stream>>>(
        Wbf + (size_t)3 * 65536, ob, Opart, Psum, image, out);
}